// Round 23
// baseline (421.460 us; speedup 1.0000x reference)
//
#include <hip/hip_runtime.h>

// LinearShift: out = round_to_fixed(x) @ v.T + round_to_fixed(bias)
// f16 MFMA GEMM, fp32 accum: absmax 0.0 validated (r7..r22).
// ROUND 23: 128x128 tile / 256 thr / 4 waves (2x2) / BK=32 / 3 LDS slots
// (48KB) -> 3 blocks/CU. Rationale: r10-r22 plateau (2430 cyc/tile) is
// lockstep phase alternation -- barrier-synced waves all read then all MFMA,
// so DS and matrix pipes never overlap. Independent co-resident blocks
// drift in phase (m114, m97) -> pipes interleave across blocks.
// Per-block schedule = r16-validated shape: 1 barrier/tile, lookahead-2,
// counted vmcnt ledger: entering tile T {T+1}=4 outstanding; stage T+2
// (+4) -> VM4 retires T+1; tail NT-2 -> VM0, NT-1 -> none; WAR: stage
// T+2 -> slot (T-1)%3, whose reads completed before BAR(T).

typedef _Float16 half8 __attribute__((ext_vector_type(8)));
typedef _Float16 half4v __attribute__((ext_vector_type(4)));
typedef float floatx4 __attribute__((ext_vector_type(4)));

__device__ __forceinline__ float qfix(float x) {
    float r = floorf(x * 256.0f + 0.5f);
    r = fminf(fmaxf(r, -32768.0f), 32767.0f);
    return r * 0.00390625f;
}

__global__ __launch_bounds__(256) void quantize_x_kernel(
        const float* __restrict__ x, _Float16* __restrict__ xq, int n4) {
    int i = blockIdx.x * 256 + threadIdx.x;
    const int stride = gridDim.x * 256;
    for (; i < n4; i += stride) {
        float4 v = reinterpret_cast<const float4*>(x)[i];
        half4v o;
        o[0] = (_Float16)qfix(v.x);
        o[1] = (_Float16)qfix(v.y);
        o[2] = (_Float16)qfix(v.z);
        o[3] = (_Float16)qfix(v.w);
        reinterpret_cast<half4v*>(xq)[i] = o;
    }
}

__global__ __launch_bounds__(256) void make_v_kernel(
        const float* __restrict__ shift, const float* __restrict__ sign,
        _Float16* __restrict__ v, int n4) {
    int i = blockIdx.x * 256 + threadIdx.x;
    const int stride = gridDim.x * 256;
    for (; i < n4; i += stride) {
        float4 sh = reinterpret_cast<const float4*>(shift)[i];
        float4 sg = reinterpret_cast<const float4*>(sign)[i];
        half4v o;
        o[0] = (_Float16)ldexpf((rintf(sg.x) == 0.0f) ? 1.0f : -1.0f, (int)rintf(sh.x));
        o[1] = (_Float16)ldexpf((rintf(sg.y) == 0.0f) ? 1.0f : -1.0f, (int)rintf(sh.y));
        o[2] = (_Float16)ldexpf((rintf(sg.z) == 0.0f) ? 1.0f : -1.0f, (int)rintf(sh.z));
        o[3] = (_Float16)ldexpf((rintf(sg.w) == 0.0f) ? 1.0f : -1.0f, (int)rintf(sh.w));
        reinterpret_cast<half4v*>(v)[i] = o;
    }
}

__device__ __forceinline__ void async_load16(const void* g, void* l) {
    __builtin_amdgcn_global_load_lds(
        (const __attribute__((address_space(1))) unsigned int*)g,
        (__attribute__((address_space(3))) unsigned int*)l,
        16, 0, 0);
}

// Stage one K-tile (A 128x32 + B 128x32 = 8192 els): 4 loads/thread.
// LDS[r][b] = G[row0+r][k0 + (b ^ ((r>>1)&3))*8]; load l covers rows
// l*64 + (t>>2), block t&3; cb is l-invariant (l*64 = 0 mod 8).
// Slot layout (els): A @ NS, B @ NS + 4096.
#define STAGE_TILE(NS)  do {                                              \
    async_load16(pA,        (NS) + t * 8);                                \
    async_load16(pA + skip, (NS) + 2048 + t * 8);                         \
    async_load16(pB,        (NS) + 4096 + t * 8);                         \
    async_load16(pB + skip, (NS) + 6144 + t * 8);                         \
    pA += 32; pB += 32; } while (0)

#define FENCE() asm volatile("" ::: "memory")
#define VM4()  do { FENCE(); __builtin_amdgcn_s_waitcnt(0x0F74); FENCE(); } while (0)
#define VM0()  do { FENCE(); __builtin_amdgcn_s_waitcnt(0x0F70); FENCE(); } while (0)
#define BAR()  do { FENCE(); __builtin_amdgcn_s_barrier(); FENCE(); } while (0)

// LDS (dynamic, 48KB): 3 slots x [A[128][32], B[128][32]] f16 (16KB/slot).
__global__ __launch_bounds__(256, 3) void gemm8_kernel(
        const _Float16* __restrict__ A,   // M x K
        const _Float16* __restrict__ B,   // N x K
        const float* __restrict__ bias,   // N
        float* __restrict__ C,            // M x N
        int M, int N, int K) {
    extern __shared__ _Float16 smem[];
    const int t = threadIdx.x;
    const int lane = t & 63;
    const int w = t >> 6;      // 0..3
    const int wrow = w >> 1;   // 0..1
    const int wcol = w & 1;    // 0..1
    const int fr  = lane & 15;
    const int kb  = lane >> 4; // 0..3

    // T1: bijective XCD swizzle (nwg = 2048, % 8 == 0)
    const int nwg = gridDim.x;
    const int bid = blockIdx.x;
    const int cpx = nwg >> 3;
    const int swz = (bid & 7) * cpx + (bid >> 3);
    const int ntN = N >> 7;    // 32
    const int bm = (swz / ntN) << 7;
    const int bn = (swz % ntN) << 7;

    // Running global stage pointers (+32 els/tile); skip = l=1 row offset.
    const int r0  = t >> 2;
    const int cbo = ((t & 3) ^ ((t >> 3) & 3)) * 8;
    const _Float16* pA = A + (size_t)(bm + r0) * K + cbo;
    const _Float16* pB = B + (size_t)(bn + r0) * K + cbo;
    const size_t skip = (size_t)64 * K;

    // Swizzled LDS read bases (bytes, slot 0): row stride 64B,
    // xk = ((kb ^ ((row>>1)&3))<<4) — r15/r16-validated formula.
    const int xk = ((kb ^ ((fr >> 1) & 3)) << 4);
    const char* sbase = (const char*)smem;
    const char* aRow = sbase +        (wrow * 64 + fr) * 64 + xk;  // + sb + mf*1024
    const char* bRow = sbase + 8192 + (wcol * 64 + fr) * 64 + xk;  // + sb + nf*1024

    // Prologue: stage tiles 0,1 into slots 0,1 (8 loads); VM4 retires tile 0.
    STAGE_TILE(smem);
    STAGE_TILE(smem + 8192);
    VM4();

    floatx4 acc[4][4] = {};   // [mf][nf]
    const int NT = K >> 5;    // 128

    for (int T = 0; T < NT; ++T) {
        BAR();
        const int sb = (T % 3) * 16384;   // slot byte offset

        half8 af[4], bf[4];
        #pragma unroll
        for (int mf = 0; mf < 4; ++mf)
            af[mf] = *reinterpret_cast<const half8*>(aRow + sb + mf * 1024);
        #pragma unroll
        for (int nf = 0; nf < 4; ++nf)
            bf[nf] = *reinterpret_cast<const half8*>(bRow + sb + nf * 1024);

        if (T + 2 < NT)
            STAGE_TILE(smem + ((T + 2) % 3) * 8192);

        #pragma unroll
        for (int mf = 0; mf < 4; ++mf)
          #pragma unroll
          for (int nf = 0; nf < 4; ++nf)
            acc[mf][nf] = __builtin_amdgcn_mfma_f32_16x16x32_f16(
                af[mf], bf[nf], acc[mf][nf], 0, 0, 0);

        if (T < NT - 2)      { VM4(); }   // retires tile T+1
        else if (T == NT - 2){ VM0(); }   // retires tile NT-1
    }

    // Epilogue: C/D layout col=lane&15, row=(lane>>4)*4+reg (validated)
    #pragma unroll
    for (int nf = 0; nf < 4; ++nf) {
        const int gcol = bn + wcol * 64 + nf * 16 + (lane & 15);
        const float bq = qfix(bias[gcol]);
        #pragma unroll
        for (int mf = 0; mf < 4; ++mf) {
            const int grow = bm + wrow * 64 + mf * 16 + ((lane >> 4) << 2);
            float* p = C + (size_t)grow * N + gcol;
            #pragma unroll
            for (int r = 0; r < 4; ++r)
                p[(size_t)r * N] = acc[mf][nf][r] + bq;
        }
    }
}

extern "C" void kernel_launch(void* const* d_in, const int* in_sizes, int n_in,
                              void* d_out, int out_size, void* d_ws, size_t ws_size,
                              hipStream_t stream) {
    const float* x     = (const float*)d_in[0];
    const float* shift = (const float*)d_in[1];
    const float* sign  = (const float*)d_in[2];
    const float* bias  = (const float*)d_in[3];
    float* out = (float*)d_out;

    const int N = in_sizes[3];            // 4096
    const int K = in_sizes[1] / N;        // 4096
    const int M = in_sizes[0] / K;        // 8192

    _Float16* xq = (_Float16*)d_ws;
    _Float16* v  = (_Float16*)((char*)d_ws + (size_t)M * K * sizeof(_Float16));

    quantize_x_kernel<<<2048, 256, 0, stream>>>(x, xq, M * K / 4);
    make_v_kernel<<<2048, 256, 0, stream>>>(shift, sign, v, N * K / 4);

    (void)hipFuncSetAttribute(reinterpret_cast<const void*>(gemm8_kernel),
                              hipFuncAttributeMaxDynamicSharedMemorySize, 49152);
    const int nblk = (M / 128) * (N / 128);   // 2048
    gemm8_kernel<<<nblk, 256, 49152, stream>>>(xq, v, bias, out, M, N, K);
}

// Round 24
// 323.587 us; speedup vs baseline: 1.3025x; 1.3025x over previous
//
#include <hip/hip_runtime.h>

// LinearShift: out = round_to_fixed(x) @ v.T + round_to_fixed(bias)
// f16 MFMA GEMM, fp32 accum, exact (absmax 0.0 validated r7..r22).
// ROUND 24: r16 skeleton (256^2, BK=32, 4 LDS slots, lookahead-3, 1 barrier
// + 1 counted-vmcnt gate per tile) with MFMA shape 16x16x32 -> 32x32x16 f16
// (2178 vs 1955 TF ubench, half the instructions). r14's NaN was the
// short8-into-bf16-builtin coercion; here operands stay half8 (_Float16).
// Frag k-map analog of validated 16x16x32: row/col = lane&31,
// k = (lane>>5)*8 + i. C/D: col=lane&31, row=(r&3)+8*(r>>2)+4*(lane>>5)
// (m74/m101 HW-verified, dtype-independent).
// r23 lesson: 128^2 tile -> HBM-bound (FETCH 1.1GB); stay 256^2.

typedef _Float16 half8 __attribute__((ext_vector_type(8)));
typedef _Float16 half4v __attribute__((ext_vector_type(4)));
typedef float floatx16 __attribute__((ext_vector_type(16)));

__device__ __forceinline__ float qfix(float x) {
    float r = floorf(x * 256.0f + 0.5f);
    r = fminf(fmaxf(r, -32768.0f), 32767.0f);
    return r * 0.00390625f;
}

__global__ __launch_bounds__(256) void quantize_x_kernel(
        const float* __restrict__ x, _Float16* __restrict__ xq, int n4) {
    int i = blockIdx.x * 256 + threadIdx.x;
    const int stride = gridDim.x * 256;
    for (; i < n4; i += stride) {
        float4 v = reinterpret_cast<const float4*>(x)[i];
        half4v o;
        o[0] = (_Float16)qfix(v.x);
        o[1] = (_Float16)qfix(v.y);
        o[2] = (_Float16)qfix(v.z);
        o[3] = (_Float16)qfix(v.w);
        reinterpret_cast<half4v*>(xq)[i] = o;
    }
}

__global__ __launch_bounds__(256) void make_v_kernel(
        const float* __restrict__ shift, const float* __restrict__ sign,
        _Float16* __restrict__ v, int n4) {
    int i = blockIdx.x * 256 + threadIdx.x;
    const int stride = gridDim.x * 256;
    for (; i < n4; i += stride) {
        float4 sh = reinterpret_cast<const float4*>(shift)[i];
        float4 sg = reinterpret_cast<const float4*>(sign)[i];
        half4v o;
        o[0] = (_Float16)ldexpf((rintf(sg.x) == 0.0f) ? 1.0f : -1.0f, (int)rintf(sh.x));
        o[1] = (_Float16)ldexpf((rintf(sg.y) == 0.0f) ? 1.0f : -1.0f, (int)rintf(sh.y));
        o[2] = (_Float16)ldexpf((rintf(sg.z) == 0.0f) ? 1.0f : -1.0f, (int)rintf(sh.z));
        o[3] = (_Float16)ldexpf((rintf(sg.w) == 0.0f) ? 1.0f : -1.0f, (int)rintf(sh.w));
        reinterpret_cast<half4v*>(v)[i] = o;
    }
}

__device__ __forceinline__ void async_load16(const void* g, void* l) {
    __builtin_amdgcn_global_load_lds(
        (const __attribute__((address_space(1))) unsigned int*)g,
        (__attribute__((address_space(3))) unsigned int*)l,
        16, 0, 0);
}

// r15/r16-validated staging: LDS[r][b] = G[row0+r][k0 + (b ^ ((r>>1)&3))*8].
#define STAGE(P, DST) async_load16((P), (DST) + t * 8)
#define STAGE_TILE(NS)  do {                                              \
    STAGE(pA0, (NS));            STAGE(pB0, (NS) + 8192);                 \
    STAGE(pB1, (NS) + 12288);    STAGE(pA1, (NS) + 4096);                 \
    pA0 += 32; pA1 += 32; pB0 += 32; pB1 += 32; } while (0)

#define FENCE() asm volatile("" ::: "memory")
#define VM8()  do { FENCE(); __builtin_amdgcn_s_waitcnt(0x0F78); FENCE(); } while (0)
#define VM4()  do { FENCE(); __builtin_amdgcn_s_waitcnt(0x0F74); FENCE(); } while (0)
#define VM0()  do { FENCE(); __builtin_amdgcn_s_waitcnt(0x0F70); FENCE(); } while (0)
#define BAR()  do { FENCE(); __builtin_amdgcn_s_barrier(); FENCE(); } while (0)

// LDS (dynamic, 128KB): 4 slots x [A0,A1,B0,B1][128][32] f16 (32KB/slot).
__global__ __launch_bounds__(512, 2) void gemm8_kernel(
        const _Float16* __restrict__ A,   // M x K
        const _Float16* __restrict__ B,   // N x K
        const float* __restrict__ bias,   // N
        float* __restrict__ C,            // M x N
        int M, int N, int K) {
    extern __shared__ _Float16 smem[];
    const int t = threadIdx.x;
    const int lane = t & 63;
    const int w = t >> 6;
    const int wrow = w >> 2;    // 0..1 : 128 output rows each
    const int wcol = w & 3;     // 0..3 : 64 output cols each
    const int fr32 = lane & 31;
    const int hi   = lane >> 5; // k-group: k = hi*8 + i

    // T1: bijective XCD swizzle (nwg = 512, % 8 == 0)
    const int nwg = gridDim.x;
    const int bid = blockIdx.x;
    const int cpx = nwg >> 3;
    const int swz = (bid & 7) * cpx + (bid >> 3);
    const int ntN = N >> 8;
    const int bm = (swz / ntN) << 8;
    const int bn = (swz % ntN) << 8;

    // Running global stage pointers (+32 els/tile), r15-validated.
    const int r0  = t >> 2;
    const int cbo = ((t & 3) ^ ((t >> 3) & 3)) * 8;
    const _Float16* pA0 = A + (size_t)(bm +       r0) * K + cbo;
    const _Float16* pA1 = A + (size_t)(bm + 128 + r0) * K + cbo;
    const _Float16* pB0 = B + (size_t)(bn +       r0) * K + cbo;
    const _Float16* pB1 = B + (size_t)(bn + 128 + r0) * K + cbo;

    // Swizzled LDS read offsets. Read k-block b = ks*2 + hi (ks = K-half),
    // un-swizzled with key (row>>1)&3; all row offsets here are multiples
    // of 32, so key = (fr32>>1)&3 (r15-derived; 0 conflicts measured).
    const int key = (fr32 >> 1) & 3;
    const int xk0 = (((0 << 1) + hi) ^ key) << 4;   // ks=0
    const int xk1 = (((1 << 1) + hi) ^ key) << 4;   // ks=1
    const char* sbase = (const char*)smem;
    // A: half = wrow (rows wrow*128 + rt*32 + fr32); A0@0, A1@8192B.
    const char* aRow = sbase + wrow * 8192 + fr32 * 64;       // + sb + rt*2048 + xk
    // B: cols wcol*64 + ct*32 + fr32; B0@16384B (cols 0-127), B1@24576B.
    const char* bRow = sbase + 16384 + (wcol >> 1) * 8192
                             + ((wcol & 1) * 64 + fr32) * 64; // + sb + ct*2048 + xk

    // Prologue: stage tiles 0,1,2 into slots 0,1,2; retire tile 0.
    STAGE_TILE(smem);
    STAGE_TILE(smem + 16384);
    STAGE_TILE(smem + 32768);
    VM8();

    floatx16 acc[4][2] = {};   // [rt][ct]
    const int NT = K >> 5;     // 128

    // r16-validated ledger: entering tile T (post gate+barrier) slot T&3 is
    // resident. Stage T+3 -> slot (T+3)&3 = (T-1)&3 (reads done pre-BAR:
    // WAR safe). Gate at tile end: T<NT-3: VM8 (out {T+1,T+2,T+3}<=12 ->
    // retires T+1); T==NT-3: VM4; T==NT-2: VM0; T==NT-1: none.
    for (int T = 0; T < NT; ++T) {
        BAR();
        const int sb = (T & 3) << 15;

        // 12 independent ds_read_b128: 8 A-frags (rt x ks), 4 B-frags (ct x ks).
        half8 af[4][2], bf[2][2];
        #pragma unroll
        for (int rt = 0; rt < 4; ++rt) {
            af[rt][0] = *reinterpret_cast<const half8*>(aRow + sb + rt * 2048 + xk0);
            af[rt][1] = *reinterpret_cast<const half8*>(aRow + sb + rt * 2048 + xk1);
        }
        #pragma unroll
        for (int ct = 0; ct < 2; ++ct) {
            bf[ct][0] = *reinterpret_cast<const half8*>(bRow + sb + ct * 2048 + xk0);
            bf[ct][1] = *reinterpret_cast<const half8*>(bRow + sb + ct * 2048 + xk1);
        }

        if (T < NT - 3)
            STAGE_TILE(smem + (((T + 3) & 3) << 14));

        // 16 x mfma_f32_32x32x16_f16 (acc += af * bf^T over K=32).
        #pragma unroll
        for (int rt = 0; rt < 4; ++rt)
          #pragma unroll
          for (int ct = 0; ct < 2; ++ct)
            #pragma unroll
            for (int ks = 0; ks < 2; ++ks)
              acc[rt][ct] = __builtin_amdgcn_mfma_f32_32x32x16_f16(
                  af[rt][ks], bf[ct][ks], acc[rt][ct], 0, 0, 0);

        if (T < NT - 3)      { VM8(); }
        else if (T == NT - 3){ VM4(); }
        else if (T == NT - 2){ VM0(); }
    }

    // Epilogue: 32x32 C/D layout col=lane&31, row=(r&3)+8*(r>>2)+4*hi
    // (m74/m101 HW-verified).
    #pragma unroll
    for (int rt = 0; rt < 4; ++rt)
      #pragma unroll
      for (int ct = 0; ct < 2; ++ct) {
          const int gcol = bn + wcol * 64 + ct * 32 + fr32;
          const float bq = qfix(bias[gcol]);
          const int grow0 = bm + wrow * 128 + rt * 32 + (hi << 2);
          #pragma unroll
          for (int r = 0; r < 16; ++r) {
              const int grow = grow0 + (r & 3) + ((r >> 2) << 3);
              C[(size_t)grow * N + gcol] = acc[rt][ct][r] + bq;
          }
      }
}

extern "C" void kernel_launch(void* const* d_in, const int* in_sizes, int n_in,
                              void* d_out, int out_size, void* d_ws, size_t ws_size,
                              hipStream_t stream) {
    const float* x     = (const float*)d_in[0];
    const float* shift = (const float*)d_in[1];
    const float* sign  = (const float*)d_in[2];
    const float* bias  = (const float*)d_in[3];
    float* out = (float*)d_out;

    const int N = in_sizes[3];            // 4096
    const int K = in_sizes[1] / N;        // 4096
    const int M = in_sizes[0] / K;        // 8192

    _Float16* xq = (_Float16*)d_ws;
    _Float16* v  = (_Float16*)((char*)d_ws + (size_t)M * K * sizeof(_Float16));

    quantize_x_kernel<<<2048, 256, 0, stream>>>(x, xq, M * K / 4);
    make_v_kernel<<<2048, 256, 0, stream>>>(shift, sign, v, N * K / 4);

    (void)hipFuncSetAttribute(reinterpret_cast<const void*>(gemm8_kernel),
                              hipFuncAttributeMaxDynamicSharedMemorySize, 131072);
    const int nblk = (M / 256) * (N / 256);   // 512
    gemm8_kernel<<<nblk, 512, 131072, stream>>>(xq, v, bias, out, M, N, K);
}

// Round 25
// 311.053 us; speedup vs baseline: 1.3549x; 1.0403x over previous
//
#include <hip/hip_runtime.h>

// LinearShift: out = round_to_fixed(x) @ v.T + round_to_fixed(bias)
// ROUND 25: r22/r16 skeleton BYTE-IDENTICAL (256^2, BK=32, 4 LDS slots,
// lookahead-3, 1 barrier + 1 counted-vmcnt gate per tile, 16x16x32 frags,
// validated swizzle, 0 bank conflicts) -- ONE variable: f16 -> bf16.
// bf16 16x16x32 ubench 2075 vs f16 1955 TF (+6% on the 1242-cyc MFMA floor).
// Guide §3 example uses short8 + mfma_f32_16x16x32_bf16 (same types here).
// Numerics: x_q int <= ~1460, bf16 quantum <= 8 -> |err| <= 2^-6/elem;
// v = +-2^k exact in bf16; dot absmax ~0.1-0.3 << 1.11 threshold.
// r24 lesson: 32x32 frags = unavoidable 4-way LDS conflict at BK=32; 16x16
// is the conflict-free shape. r14's NaN: 3 confounded vars; r24 cleared
// the k-map and C/D layout; this round isolates dtype.

typedef short short8 __attribute__((ext_vector_type(8)));   // 8 bf16
typedef unsigned short ushort4v __attribute__((ext_vector_type(4)));
typedef float floatx4 __attribute__((ext_vector_type(4)));

__device__ __forceinline__ float qfix(float x) {
    float r = floorf(x * 256.0f + 0.5f);
    r = fminf(fmaxf(r, -32768.0f), 32767.0f);
    return r * 0.00390625f;
}

// float -> bf16 bits, round-nearest-even (inputs finite).
__device__ __forceinline__ unsigned short f2bf(float f) {
    unsigned int b = __builtin_bit_cast(unsigned int, f);
    b += 0x7FFFu + ((b >> 16) & 1u);
    return (unsigned short)(b >> 16);
}

__global__ __launch_bounds__(256) void quantize_x_kernel(
        const float* __restrict__ x, unsigned short* __restrict__ xq, int n4) {
    int i = blockIdx.x * 256 + threadIdx.x;
    const int stride = gridDim.x * 256;
    for (; i < n4; i += stride) {
        float4 v = reinterpret_cast<const float4*>(x)[i];
        ushort4v o;
        o[0] = f2bf(qfix(v.x));
        o[1] = f2bf(qfix(v.y));
        o[2] = f2bf(qfix(v.z));
        o[3] = f2bf(qfix(v.w));
        reinterpret_cast<ushort4v*>(xq)[i] = o;
    }
}

__global__ __launch_bounds__(256) void make_v_kernel(
        const float* __restrict__ shift, const float* __restrict__ sign,
        unsigned short* __restrict__ v, int n4) {
    int i = blockIdx.x * 256 + threadIdx.x;
    const int stride = gridDim.x * 256;
    for (; i < n4; i += stride) {
        float4 sh = reinterpret_cast<const float4*>(shift)[i];
        float4 sg = reinterpret_cast<const float4*>(sign)[i];
        ushort4v o;
        o[0] = f2bf(ldexpf((rintf(sg.x) == 0.0f) ? 1.0f : -1.0f, (int)rintf(sh.x)));
        o[1] = f2bf(ldexpf((rintf(sg.y) == 0.0f) ? 1.0f : -1.0f, (int)rintf(sh.y)));
        o[2] = f2bf(ldexpf((rintf(sg.z) == 0.0f) ? 1.0f : -1.0f, (int)rintf(sh.z)));
        o[3] = f2bf(ldexpf((rintf(sg.w) == 0.0f) ? 1.0f : -1.0f, (int)rintf(sh.w)));
        reinterpret_cast<ushort4v*>(v)[i] = o;
    }
}

__device__ __forceinline__ void async_load16(const void* g, void* l) {
    __builtin_amdgcn_global_load_lds(
        (const __attribute__((address_space(1))) unsigned int*)g,
        (__attribute__((address_space(3))) unsigned int*)l,
        16, 0, 0);
}

// r15/r16-validated staging: LDS[r][b] = G[row0+r][k0 + (b ^ ((r>>1)&3))*8].
#define STAGE(P, DST) async_load16((P), (DST) + t * 8)
#define STAGE_TILE(NS)  do {                                              \
    STAGE(pA0, (NS));            STAGE(pB0, (NS) + 8192);                 \
    STAGE(pB1, (NS) + 12288);    STAGE(pA1, (NS) + 4096);                 \
    pA0 += 32; pA1 += 32; pB0 += 32; pB1 += 32; } while (0)

#define FENCE() asm volatile("" ::: "memory")
#define VM8()  do { FENCE(); __builtin_amdgcn_s_waitcnt(0x0F78); FENCE(); } while (0)
#define VM4()  do { FENCE(); __builtin_amdgcn_s_waitcnt(0x0F74); FENCE(); } while (0)
#define VM0()  do { FENCE(); __builtin_amdgcn_s_waitcnt(0x0F70); FENCE(); } while (0)
#define BAR()  do { FENCE(); __builtin_amdgcn_s_barrier(); FENCE(); } while (0)

// LDS (dynamic, 128KB): 4 slots x [A0,A1,B0,B1][128][32] bf16 (32KB/slot).
__global__ __launch_bounds__(512, 2) void gemm8_kernel(
        const unsigned short* __restrict__ A,   // M x K (bf16 bits)
        const unsigned short* __restrict__ B,   // N x K (bf16 bits)
        const float* __restrict__ bias,         // N
        float* __restrict__ C,                  // M x N
        int M, int N, int K) {
    extern __shared__ unsigned short smem[];
    const int t = threadIdx.x;
    const int lane = t & 63;
    const int w = t >> 6;
    const int wrow = w >> 2;   // 0..1
    const int wcol = w & 3;    // 0..3
    const int fr  = lane & 15;
    const int kb  = lane >> 4; // 0..3

    // T1: bijective XCD swizzle (nwg = 512, % 8 == 0)
    const int nwg = gridDim.x;
    const int bid = blockIdx.x;
    const int cpx = nwg >> 3;
    const int swz = (bid & 7) * cpx + (bid >> 3);
    const int ntN = N >> 8;
    const int bm = (swz / ntN) << 8;
    const int bn = (swz % ntN) << 8;

    // Running global stage pointers (+32 els/tile), r15-validated.
    const int r0  = t >> 2;
    const int cbo = ((t & 3) ^ ((t >> 3) & 3)) * 8;
    const unsigned short* pA0 = A + (size_t)(bm +       r0) * K + cbo;
    const unsigned short* pA1 = A + (size_t)(bm + 128 + r0) * K + cbo;
    const unsigned short* pB0 = B + (size_t)(bn +       r0) * K + cbo;
    const unsigned short* pB1 = B + (size_t)(bn + 128 + r0) * K + cbo;

    // Precomputed swizzled LDS read bases (bytes, slot 0), r15-validated:
    // read byte = row*64 + ((kb ^ ((row>>1)&3))<<4).
    const int xk = ((kb ^ ((fr >> 1) & 3)) << 4);
    const char* sbase = (const char*)smem;
    const char* aRow = sbase + (wrow * 64 + fr) * 64 + xk;               // +q*8192 +mf*1024
    const char* bR0  = sbase + 16384 + (wcol * 32 +      fr) * 64 + xk;  // +qn*8192
    const char* bR1  = sbase + 16384 + (wcol * 32 + 16 + fr) * 64 + xk;

    // Prologue: stage tiles 0,1,2 into slots 0,1,2; retire tile 0.
    STAGE_TILE(smem);
    STAGE_TILE(smem + 16384);
    STAGE_TILE(smem + 32768);
    VM8();

    floatx4 acc[2][2][4][2] = {};   // [qm][qn][mf][nf] — all static-indexed
    const int NT = K >> 5;          // 128

    // r16-validated ledger: entering tile T (post gate+barrier) slot T&3
    // resident. Stage T+3 -> slot (T+3)&3 = (T-1)&3 (WAR safe: reads done
    // pre-BAR). Gate: T<NT-3: VM8 (retires T+1); NT-3: VM4; NT-2: VM0;
    // NT-1: none.
    for (int T = 0; T < NT; ++T) {
        BAR();
        const int sb = (T & 3) << 15;   // read-slot byte offset

        // 12 independent ds_read_b128 (conflict-free, measured r16/r22).
        short8 af0[4], af1[4], bf0[2], bf1[2];
        #pragma unroll
        for (int mf = 0; mf < 4; ++mf) {
            af0[mf] = *reinterpret_cast<const short8*>(aRow + sb +        mf * 1024);
            af1[mf] = *reinterpret_cast<const short8*>(aRow + sb + 8192 + mf * 1024);
        }
        bf0[0] = *reinterpret_cast<const short8*>(bR0 + sb);
        bf0[1] = *reinterpret_cast<const short8*>(bR1 + sb);
        bf1[0] = *reinterpret_cast<const short8*>(bR0 + sb + 8192);
        bf1[1] = *reinterpret_cast<const short8*>(bR1 + sb + 8192);

        if (T < NT - 3)
            STAGE_TILE(smem + (((T + 3) & 3) << 14));

        #pragma unroll
        for (int mf = 0; mf < 4; ++mf)
          #pragma unroll
          for (int nf = 0; nf < 2; ++nf) {
            acc[0][0][mf][nf] = __builtin_amdgcn_mfma_f32_16x16x32_bf16(
                af0[mf], bf0[nf], acc[0][0][mf][nf], 0, 0, 0);
            acc[0][1][mf][nf] = __builtin_amdgcn_mfma_f32_16x16x32_bf16(
                af0[mf], bf1[nf], acc[0][1][mf][nf], 0, 0, 0);
            acc[1][1][mf][nf] = __builtin_amdgcn_mfma_f32_16x16x32_bf16(
                af1[mf], bf1[nf], acc[1][1][mf][nf], 0, 0, 0);
            acc[1][0][mf][nf] = __builtin_amdgcn_mfma_f32_16x16x32_bf16(
                af1[mf], bf0[nf], acc[1][0][mf][nf], 0, 0, 0);
          }

        if (T < NT - 3)      { VM8(); }
        else if (T == NT - 3){ VM4(); }
        else if (T == NT - 2){ VM0(); }
    }

    // Epilogue: C/D layout col=lane&15, row=(lane>>4)*4+reg (validated)
    #pragma unroll
    for (int qm = 0; qm < 2; ++qm)
      #pragma unroll
      for (int qn = 0; qn < 2; ++qn)
        #pragma unroll
        for (int nf = 0; nf < 2; ++nf) {
            const int gcol = bn + qn * 128 + wcol * 32 + nf * 16 + (lane & 15);
            const float bq = qfix(bias[gcol]);
            #pragma unroll
            for (int mf = 0; mf < 4; ++mf) {
                const int grow = bm + qm * 128 + wrow * 64 + mf * 16 + ((lane >> 4) << 2);
                float* p = C + (size_t)grow * N + gcol;
                #pragma unroll
                for (int r = 0; r < 4; ++r)
                    p[(size_t)r * N] = acc[qm][qn][mf][nf][r] + bq;
            }
        }
}

extern "C" void kernel_launch(void* const* d_in, const int* in_sizes, int n_in,
                              void* d_out, int out_size, void* d_ws, size_t ws_size,
                              hipStream_t stream) {
    const float* x     = (const float*)d_in[0];
    const float* shift = (const float*)d_in[1];
    const float* sign  = (const float*)d_in[2];
    const float* bias  = (const float*)d_in[3];
    float* out = (float*)d_out;

    const int N = in_sizes[3];            // 4096
    const int K = in_sizes[1] / N;        // 4096
    const int M = in_sizes[0] / K;        // 8192

    unsigned short* xq = (unsigned short*)d_ws;
    unsigned short* v  = xq + (size_t)M * K;

    quantize_x_kernel<<<2048, 256, 0, stream>>>(x, xq, M * K / 4);
    make_v_kernel<<<2048, 256, 0, stream>>>(shift, sign, v, N * K / 4);

    (void)hipFuncSetAttribute(reinterpret_cast<const void*>(gemm8_kernel),
                              hipFuncAttributeMaxDynamicSharedMemorySize, 131072);
    const int nblk = (M / 256) * (N / 256);   // 512
    gemm8_kernel<<<nblk, 512, 131072, stream>>>(xq, v, bias, out, M, N, K);
}